// Round 23
// baseline (136.328 us; speedup 1.0000x reference)
//
#include <hip/hip_runtime.h>
#include <cmath>

#define TT 1024
#define HH 8
#define KVHN 4

typedef unsigned short u16;
typedef __attribute__((ext_vector_type(8))) short bf16x8;
typedef __attribute__((ext_vector_type(4))) float f32x4;

#define MFMA(a, b, c) __builtin_amdgcn_mfma_f32_16x16x32_bf16(a, b, c, 0, 0, 0)

__device__ __forceinline__ float bflo(unsigned u) { return __uint_as_float(u << 16); }
__device__ __forceinline__ float bfhi(unsigned u) { return __uint_as_float(u & 0xffff0000u); }
__device__ __forceinline__ u16 bfr(float f) {
  unsigned u = __float_as_uint(f);
  return (u16)((u + 0x7fffu + ((u >> 16) & 1u)) >> 16);
}
__device__ __forceinline__ float hpart(u16 h) {
  return __uint_as_float((unsigned)h << 16);
}

__device__ __forceinline__ bf16x8 ld8_g(const u16* __restrict__ p) {
  uint4 v = *reinterpret_cast<const uint4*>(p);
  return __builtin_bit_cast(bf16x8, v);
}
__device__ __forceinline__ bf16x8 ld8_lds(const u16* s, int col, int k8) {
  const uint4* p = reinterpret_cast<const uint4*>(s);
  return __builtin_bit_cast(bf16x8, p[col * 8 + (k8 ^ (col & 7))]);
}
__device__ __forceinline__ void st_split_lds(u16* sh, u16* sl, int col, int r0,
                                             f32x4 v) {
  u16 hh[4], ll[4];
#pragma unroll
  for (int j = 0; j < 4; ++j) {
    u16 hb = bfr(v[j]);
    hh[j] = hb;
    ll[j] = bfr(v[j] - hpart(hb));
  }
  uint2 ph, pl;
  ph.x = (unsigned)hh[0] | ((unsigned)hh[1] << 16);
  ph.y = (unsigned)hh[2] | ((unsigned)hh[3] << 16);
  pl.x = (unsigned)ll[0] | ((unsigned)ll[1] << 16);
  pl.y = (unsigned)ll[2] | ((unsigned)ll[3] << 16);
  int idx = col * 64 + (((r0 >> 3) ^ (col & 7)) << 3) + (r0 & 7);
  *reinterpret_cast<uint2*>(sh + idx) = ph;
  *reinterpret_cast<uint2*>(sl + idx) = pl;
}
// split 8 f32 (two float4) into hi/lo bf16x8
__device__ __forceinline__ void cvt8v(float4 a, float4 b, bf16x8& h, bf16x8& l) {
  float v[8] = {a.x, a.y, a.z, a.w, b.x, b.y, b.z, b.w};
  unsigned hh[8], ll[8];
#pragma unroll
  for (int j = 0; j < 8; ++j) {
    u16 hb = bfr(v[j]);
    hh[j] = hb;
    ll[j] = bfr(v[j] - hpart(hb));
  }
  uint4 H, L;
  H.x = hh[0] | (hh[1] << 16); H.y = hh[2] | (hh[3] << 16);
  H.z = hh[4] | (hh[5] << 16); H.w = hh[6] | (hh[7] << 16);
  L.x = ll[0] | (ll[1] << 16); L.y = ll[2] | (ll[3] << 16);
  L.z = ll[4] | (ll[5] << 16); L.w = ll[6] | (ll[7] << 16);
  h = __builtin_bit_cast(bf16x8, H);
  l = __builtin_bit_cast(bf16x8, L);
}
// load 8 consecutive f32, split into hi/lo bf16x8
__device__ __forceinline__ void cvt8(const float* __restrict__ p, bf16x8& h,
                                     bf16x8& l) {
  float4 a = *reinterpret_cast<const float4*>(p);
  float4 b = *reinterpret_cast<const float4*>(p + 4);
  cvt8v(a, b, h, l);
}

// ---------------------------------------------------------------------------
// K0: prep — transpose+split WEIGHTS ONLY to bf16 hi/lo [n][k]. Grid (8, 24).
// (x conversion now fused into qkv staging.)
// ---------------------------------------------------------------------------
__global__ __launch_bounds__(256) void prep_kernel(
    const float* __restrict__ Wq, const float* __restrict__ Wk,
    const float* __restrict__ Wv, const float* __restrict__ Wo,
    u16* __restrict__ WtH, u16* __restrict__ WtL, u16* __restrict__ WotH,
    u16* __restrict__ WotL) {
  const int kt = blockIdx.x, nt = blockIdx.y;
  const int tid = threadIdx.x;
  const int k0 = kt * 64;

  const float* Wsel;
  int wstride, wc0;
  u16 *oh, *ol;
  if (nt < 16) {
    if (nt < 8) { Wsel = Wq; wstride = 512; wc0 = nt * 64; }
    else if (nt < 12) { Wsel = Wk; wstride = 256; wc0 = (nt - 8) * 64; }
    else { Wsel = Wv; wstride = 256; wc0 = (nt - 12) * 64; }
    oh = WtH + (size_t)(nt * 64) * 512;
    ol = WtL + (size_t)(nt * 64) * 512;
  } else {
    Wsel = Wo; wstride = 512; wc0 = (nt - 16) * 64;
    oh = WotH + (size_t)((nt - 16) * 64) * 512;
    ol = WotL + (size_t)((nt - 16) * 64) * 512;
  }

  __shared__ float Ws[64][68];
#pragma unroll
  for (int m = 0; m < 4; ++m) {
    int f = m * 256 + tid;
    int rr = f >> 4, dc = (f & 15) * 4;
    *reinterpret_cast<float4*>(&Ws[rr][dc]) =
        *reinterpret_cast<const float4*>(Wsel + (size_t)(k0 + rr) * wstride + wc0 + dc);
  }
  __syncthreads();

  const int nr = tid >> 2, kc0 = (tid & 3) * 16;
  u16* dh = oh + (size_t)nr * 512 + k0 + kc0;
  u16* dl = ol + (size_t)nr * 512 + k0 + kc0;
#pragma unroll
  for (int i = 0; i < 16; i += 2) {
    float a = Ws[kc0 + i][nr], b = Ws[kc0 + i + 1][nr];
    u16 ha = bfr(a), hb2 = bfr(b);
    u16 la = bfr(a - hpart(ha));
    u16 lb = bfr(b - hpart(hb2));
    *reinterpret_cast<unsigned*>(dh + i) = (unsigned)ha | ((unsigned)hb2 << 16);
    *reinterpret_cast<unsigned*>(dl + i) = (unsigned)la | ((unsigned)lb << 16);
  }
}

// ---------------------------------------------------------------------------
// K1: QKV via MFMA, 128x64 LDS-staged tile; x f32 -> hi/lo DURING staging
// (out_proj-proven pattern). Grid (16 cy, 16 rt), 512 thr. In-register RoPE.
// ---------------------------------------------------------------------------
__global__ __launch_bounds__(512) void qkv_mfma_kernel(
    const float* __restrict__ x, const u16* __restrict__ WtH,
    const u16* __restrict__ WtL, const float* __restrict__ cosb,
    const float* __restrict__ sinb, float* __restrict__ Q,
    float* __restrict__ Kt, float* __restrict__ Vt) {
  const int cy = blockIdx.x, rt = blockIdx.y;
  const int tid = threadIdx.x;
  const int lane = tid & 63, w = tid >> 6;
  const int ln = lane & 15, kg = lane >> 4;
  const int n0 = cy * 64, m0 = rt * 128;

  __shared__ u16 XHs[128 * 64], XLs[128 * 64];
  __shared__ u16 WHs[64 * 64], WLs[64 * 64];

  auto LD8T = [&](const u16* s, int row, int k8) {
    return __builtin_bit_cast(
        bf16x8, reinterpret_cast<const uint4*>(s)[row * 8 + (k8 ^ (row & 7))]);
  };

  f32x4 acc[4];
#pragma unroll
  for (int ct = 0; ct < 4; ++ct) acc[ct] = {0.f, 0.f, 0.f, 0.f};

  for (int c = 0; c < 8; ++c) {
    const int k0 = c * 64;
    __syncthreads();
#pragma unroll
    for (int m = 0; m < 2; ++m) {
      int f = m * 512 + tid;
      int srow = f >> 3, sk8 = f & 7;
      int slot = srow * 8 + (sk8 ^ (srow & 7));
      const float* xp = x + (size_t)(m0 + srow) * 512 + k0 + sk8 * 8;
      bf16x8 h, l;
      cvt8(xp, h, l);
      reinterpret_cast<uint4*>(XHs)[slot] = __builtin_bit_cast(uint4, h);
      reinterpret_cast<uint4*>(XLs)[slot] = __builtin_bit_cast(uint4, l);
    }
    {
      int wrow = tid >> 3, wk8 = tid & 7;
      int slot = wrow * 8 + (wk8 ^ (wrow & 7));
      reinterpret_cast<uint4*>(WHs)[slot] = *reinterpret_cast<const uint4*>(
          WtH + (size_t)(n0 + wrow) * 512 + k0 + wk8 * 8);
      reinterpret_cast<uint4*>(WLs)[slot] = *reinterpret_cast<const uint4*>(
          WtL + (size_t)(n0 + wrow) * 512 + k0 + wk8 * 8);
    }
    __syncthreads();

#pragma unroll
    for (int win = 0; win < 2; ++win) {
      int k8a = win * 4 + kg;
      bf16x8 ah = LD8T(XHs, w * 16 + ln, k8a);
      bf16x8 al = LD8T(XLs, w * 16 + ln, k8a);
#pragma unroll
      for (int ct = 0; ct < 4; ++ct) {
        bf16x8 bh = LD8T(WHs, ct * 16 + ln, k8a);
        bf16x8 bl = LD8T(WLs, ct * 16 + ln, k8a);
        acc[ct] = MFMA(ah, bh, acc[ct]);
        acc[ct] = MFMA(al, bh, acc[ct]);
        acc[ct] = MFMA(ah, bl, acc[ct]);
      }
    }
  }

  const int trow0 = m0 + w * 16 + kg * 4;
  if (cy < 12) {
#pragma unroll
    for (int j = 0; j < 4; ++j) {
      int row = trow0 + j, b = row >> 10, t = row & 1023;
      float* OP;
      size_t base;
      if (cy < 8) {
        OP = Q;
        base = ((size_t)(b * HH + cy) * TT + t) * 64;
      } else {
        OP = Kt;
        base = ((size_t)(b * KVHN + (cy - 8)) * TT + t) * 64;
      }
#pragma unroll
      for (int ct = 0; ct < 2; ++ct) {
        int dd = ct * 16 + ln;
        float cc = cosb[t * 32 + dd], ss = sinb[t * 32 + dd];
        float v1 = acc[ct][j], v2 = acc[ct + 2][j];
        OP[base + dd] = v1 * cc + v2 * ss;
        OP[base + 32 + dd] = v2 * cc - v1 * ss;
      }
    }
  } else {
#pragma unroll
    for (int j = 0; j < 4; ++j) {
      int row = trow0 + j, b = row >> 10, t = row & 1023;
      size_t base = ((size_t)(b * KVHN + (cy - 12)) * TT + t) * 64;
#pragma unroll
      for (int ct = 0; ct < 4; ++ct) Vt[base + ct * 16 + ln] = acc[ct][j];
    }
  }
}

// ---------------------------------------------------------------------------
// K2: MFMA causal logits + exp -> A (bf16). Grid (16 sys, 136 n). (r20)
// ---------------------------------------------------------------------------
__global__ __launch_bounds__(256) void logits_mfma_kernel(
    const float* __restrict__ Q, const float* __restrict__ Kt,
    u16* __restrict__ A, float* __restrict__ part) {
  const int sys = blockIdx.x, n = blockIdx.y;
  int it = 0;
  while ((it + 1) * (it + 2) / 2 <= n) ++it;
  const int jt = n - it * (it + 1) / 2;
  const int b = sys >> 3, kvh = (sys & 7) >> 1;
  const int tid = threadIdx.x;
  const int lane = tid & 63, w = tid >> 6;
  const int ln = lane & 15, kg = lane >> 4;
  const int m0 = w * 16;

  const float* Qr = Q + ((size_t)sys * TT + it * 64 + m0 + ln) * 64;
  const float* Kb = Kt + ((size_t)(b * KVHN + kvh) * TT + jt * 64) * 64;
  u16* Aout = A + ((size_t)sys << 20);

  bf16x8 qh0, ql0, qh1, ql1;
  cvt8(Qr + kg * 8, qh0, ql0);
  cvt8(Qr + 32 + kg * 8, qh1, ql1);

  f32x4 acc[4];
#pragma unroll
  for (int ct = 0; ct < 4; ++ct) {
    const float* Kr = Kb + (size_t)(ct * 16 + ln) * 64;
    bf16x8 kh0, kl0, kh1, kl1;
    cvt8(Kr + kg * 8, kh0, kl0);
    cvt8(Kr + 32 + kg * 8, kh1, kl1);
    f32x4 a = {0.f, 0.f, 0.f, 0.f};
    a = MFMA(qh0, kh0, a);
    a = MFMA(qh1, kh1, a);
    a = MFMA(qh0, kl0, a);
    a = MFMA(qh1, kl1, a);
    a = MFMA(ql0, kh0, a);
    a = MFMA(ql1, kh1, a);
    acc[ct] = a;
  }

  const int grow0 = it * 64 + m0;
  const bool full = (jt < it);
  float s[4] = {0.f, 0.f, 0.f, 0.f};
#pragma unroll
  for (int ct = 0; ct < 4; ++ct) {
    int col = jt * 64 + ct * 16 + ln;
#pragma unroll
    for (int j = 0; j < 4; ++j) {
      int row = grow0 + kg * 4 + j;
      float e = (full || col <= row) ? __expf(acc[ct][j] * 0.125f) : 0.f;
      s[j] += e;
      Aout[(size_t)row * 1024 + col] = bfr(e);
    }
  }

#pragma unroll
  for (int off = 1; off < 16; off <<= 1) {
#pragma unroll
    for (int j = 0; j < 4; ++j) s[j] += __shfl_xor(s[j], off);
  }
  if (ln == 0) {
#pragma unroll
    for (int j = 0; j < 4; ++j)
      part[((size_t)(sys * 16 + jt)) * 1024 + grow0 + kg * 4 + j] = s[j];
  }
}

// ---------------------------------------------------------------------------
// K3a: barrier-free one-wave diag-block inversion. (round-15 proven)
// ---------------------------------------------------------------------------
__global__ __launch_bounds__(64) void diaginv_kernel(
    u16* __restrict__ A, const float* __restrict__ part,
    float* __restrict__ invs) {
  const int k = blockIdx.x, sys = blockIdx.y;
  const int c = threadIdx.x;

  u16* Ab = A + ((size_t)sys << 20) + (size_t)(k * 64) * 1024 + k * 64;

  __shared__ float MsT[64][68];
  __shared__ float dv[64];

  {
    const int r = c;
    float row[64];
#pragma unroll
    for (int m8 = 0; m8 < 8; ++m8) {
      uint4 v = *reinterpret_cast<const uint4*>(Ab + (size_t)r * 1024 + m8 * 8);
      row[m8 * 8 + 0] = bflo(v.x); row[m8 * 8 + 1] = bfhi(v.x);
      row[m8 * 8 + 2] = bflo(v.y); row[m8 * 8 + 3] = bfhi(v.y);
      row[m8 * 8 + 4] = bflo(v.z); row[m8 * 8 + 5] = bfhi(v.z);
      row[m8 * 8 + 6] = bflo(v.w); row[m8 * 8 + 7] = bfhi(v.w);
    }
    float s = 0.f;
    for (int jt = 0; jt <= k; ++jt)
      s += part[((size_t)(sys * 16 + jt)) * 1024 + k * 64 + r];
    float svr = 1.0f / s;
    invs[sys * 1024 + k * 64 + r] = svr;
    dv[r] = 1.0f / (1.0f + svr * row[r]);
#pragma unroll
    for (int j = 0; j < 64; ++j) MsT[j][r] = svr * row[j];
  }
  __syncthreads();

  float dvr[64];
#pragma unroll
  for (int q = 0; q < 64; ++q) dvr[q] = dv[q];

  float w[64], acc[64];
#pragma unroll
  for (int r = 0; r < 64; ++r) acc[r] = 0.f;

#pragma unroll
  for (int r = 0; r < 64; ++r) {
    float wr = ((r == c) ? 1.0f : 0.0f) - acc[r];
    wr *= dvr[r];
    w[r] = wr;
#pragma unroll
    for (int q = (r + 1) >> 2; q < 16; ++q) {
      float4 m4 = *reinterpret_cast<const float4*>(&MsT[r][q * 4]);
      acc[q * 4 + 0] += m4.x * wr;
      acc[q * 4 + 1] += m4.y * wr;
      acc[q * 4 + 2] += m4.z * wr;
      acc[q * 4 + 3] += m4.w * wr;
    }
  }

#pragma unroll
  for (int r = 0; r < 64; ++r) Ab[(size_t)r * 1024 + c] = bfr(w[r]);
}

// ---------------------------------------------------------------------------
// K3b: right-looking MFMA solve — r16 structure; ONLY change: Yg stores
// moved from phase 2 (pre-B2) to after B2, overlapping phase 3 (drain at B3).
// ---------------------------------------------------------------------------
__global__ __launch_bounds__(1024) void solve_mfma_kernel(
    const u16* __restrict__ A, const float* __restrict__ invs,
    const float* __restrict__ Vt, float* __restrict__ Yout) {
  const int sys = blockIdx.x, cq = blockIdx.y;
  const int bb = sys >> 3, kvh = (sys & 7) >> 1;
  const int c0 = cq * 16;
  const int tid = threadIdx.x;
  const int lane = tid & 63, w = tid >> 6;
  const int ln = lane & 15, kg = lane >> 4;

  const u16* Ab = A + ((size_t)sys << 20);
  const float* Vb = Vt + ((size_t)(bb * KVHN + kvh) * TT) * 64;
  float* Yg = Yout + (size_t)sys * TT * 64;

  __shared__ float U[16][1031];
  __shared__ u16 yh[16 * 64], yl[16 * 64];
  __shared__ u16 uh[16 * 64], ul[16 * 64];

  {
    float* Uf = &U[0][0];
    for (int i = tid; i < 16 * 1031; i += 1024) Uf[i] = 0.f;
  }
  __syncthreads();

  for (int k = 0; k < 16; ++k) {
    const int rg0 = k * 64;

    uint4 pm0 = {}, pm1 = {};
    f32x4 pv = {0.f, 0.f, 0.f, 0.f}, psi = {0.f, 0.f, 0.f, 0.f};
    if (w < 4) {
      const u16* mrow = Ab + (size_t)(rg0 + w * 16 + ln) * 1024 + rg0;
      pm0 = *reinterpret_cast<const uint4*>(mrow + kg * 8);
      pm1 = *reinterpret_cast<const uint4*>(mrow + 32 + kg * 8);
#pragma unroll
      for (int j = 0; j < 4; ++j) {
        int gr = rg0 + w * 16 + kg * 4 + j;
        pv[j] = Vb[(size_t)gr * 64 + c0 + ln];
        psi[j] = invs[sys * 1024 + gr];
      }
    }
    const int nu = (15 - k) * 4;
    uint4 pa0[4], pa1[4];
    bool val[4];
#pragma unroll
    for (int t = 0; t < 4; ++t) {
      int un = w + 16 * t;
      val[t] = un < nu;
      if (val[t]) {
        const u16* ar =
            Ab + (size_t)((k + 1 + (un >> 2)) * 64 + (un & 3) * 16 + ln) * 1024 +
            rg0;
        pa0[t] = *reinterpret_cast<const uint4*>(ar + kg * 8);
        pa1[t] = *reinterpret_cast<const uint4*>(ar + 32 + kg * 8);
      }
    }
    __builtin_amdgcn_sched_barrier(0);  // pin: loads issue BEFORE phases

    if (w < 4) {
      f32x4 u;
#pragma unroll
      for (int j = 0; j < 4; ++j) {
        int gr = rg0 + w * 16 + kg * 4 + j;
        u[j] = pv[j] - psi[j] * U[ln][gr];
      }
      st_split_lds(uh, ul, ln, w * 16 + kg * 4, u);
    }
    __syncthreads();

    f32x4 y = {0.f, 0.f, 0.f, 0.f};
    if (w < 4) {
      bf16x8 ma0 = __builtin_bit_cast(bf16x8, pm0);
      bf16x8 ma1 = __builtin_bit_cast(bf16x8, pm1);
      y = MFMA(ma0, ld8_lds(uh, ln, kg), y);
      y = MFMA(ma1, ld8_lds(uh, ln, 4 + kg), y);
      y = MFMA(ma0, ld8_lds(ul, ln, kg), y);
      y = MFMA(ma1, ld8_lds(ul, ln, 4 + kg), y);
      st_split_lds(yh, yl, ln, w * 16 + kg * 4, y);
    }
    __syncthreads();

    // Yg stores AFTER B2: overlap phase-3 MFMA, drain at B3.
    if (w < 4) {
#pragma unroll
      for (int j = 0; j < 4; ++j)
        Yg[(size_t)(rg0 + w * 16 + kg * 4 + j) * 64 + c0 + ln] = y[j];
    }

#pragma unroll
    for (int t = 0; t < 4; ++t) {
      if (val[t]) {
        int un = w + 16 * t;
        int rb = (k + 1 + (un >> 2)) * 64 + (un & 3) * 16 + kg * 4;
        bf16x8 a0 = __builtin_bit_cast(bf16x8, pa0[t]);
        bf16x8 a1 = __builtin_bit_cast(bf16x8, pa1[t]);
        f32x4 s = {0.f, 0.f, 0.f, 0.f};
        s = MFMA(a0, ld8_lds(yh, ln, kg), s);
        s = MFMA(a1, ld8_lds(yh, ln, 4 + kg), s);
        s = MFMA(a0, ld8_lds(yl, ln, kg), s);
        s = MFMA(a1, ld8_lds(yl, ln, 4 + kg), s);
#pragma unroll
        for (int j = 0; j < 4; ++j) U[ln][rb + j] += s[j];
      }
    }
    __syncthreads();
  }
}

// ---------------------------------------------------------------------------
// K4: out = x + Y2d @ Wo via MFMA, 128x64 LDS-staged tile. (round-22 proven)
// ---------------------------------------------------------------------------
__global__ __launch_bounds__(512) void out_proj_mfma_kernel(
    const float* __restrict__ Y, const u16* __restrict__ WotH,
    const u16* __restrict__ WotL, const float* __restrict__ x,
    float* __restrict__ out) {
  const int cy = blockIdx.x, rt = blockIdx.y;
  const int tid = threadIdx.x;
  const int lane = tid & 63, w = tid >> 6;
  const int ln = lane & 15, kg = lane >> 4;
  const int n0 = cy * 64, m0 = rt * 128;

  __shared__ u16 YHs[128 * 64], YLs[128 * 64];
  __shared__ u16 WHs[64 * 64], WLs[64 * 64];

  auto LD8T = [&](const u16* s, int row, int k8) {
    return __builtin_bit_cast(
        bf16x8, reinterpret_cast<const uint4*>(s)[row * 8 + (k8 ^ (row & 7))]);
  };

  f32x4 acc[4];
#pragma unroll
  for (int ct = 0; ct < 4; ++ct) acc[ct] = {0.f, 0.f, 0.f, 0.f};

  for (int c = 0; c < 8; ++c) {
    const int k0 = c * 64;
    __syncthreads();
#pragma unroll
    for (int m = 0; m < 2; ++m) {
      int f = m * 512 + tid;
      int srow = f >> 3, sk8 = f & 7;
      int slot = srow * 8 + (sk8 ^ (srow & 7));
      int row = m0 + srow, b = row >> 10, t = row & 1023;
      const float* yp = Y + ((size_t)(b * HH + c) * TT + t) * 64 + sk8 * 8;
      bf16x8 h, l;
      cvt8(yp, h, l);
      reinterpret_cast<uint4*>(YHs)[slot] = __builtin_bit_cast(uint4, h);
      reinterpret_cast<uint4*>(YLs)[slot] = __builtin_bit_cast(uint4, l);
    }
    {
      int wrow = tid >> 3, wk8 = tid & 7;
      int slot = wrow * 8 + (wk8 ^ (wrow & 7));
      reinterpret_cast<uint4*>(WHs)[slot] = *reinterpret_cast<const uint4*>(
          WotH + (size_t)(n0 + wrow) * 512 + k0 + wk8 * 8);
      reinterpret_cast<uint4*>(WLs)[slot] = *reinterpret_cast<const uint4*>(
          WotL + (size_t)(n0 + wrow) * 512 + k0 + wk8 * 8);
    }
    __syncthreads();

#pragma unroll
    for (int win = 0; win < 2; ++win) {
      int k8a = win * 4 + kg;
      bf16x8 ah = LD8T(YHs, w * 16 + ln, k8a);
      bf16x8 al = LD8T(YLs, w * 16 + ln, k8a);
#pragma unroll
      for (int ct = 0; ct < 4; ++ct) {
        bf16x8 bh = LD8T(WHs, ct * 16 + ln, k8a);
        bf16x8 bl = LD8T(WLs, ct * 16 + ln, k8a);
        acc[ct] = MFMA(ah, bh, acc[ct]);
        acc[ct] = MFMA(al, bh, acc[ct]);
        acc[ct] = MFMA(ah, bl, acc[ct]);
      }
    }
  }

  const int trow0 = m0 + w * 16 + kg * 4;
#pragma unroll
  for (int j = 0; j < 4; ++j) {
    size_t row = (size_t)(trow0 + j);
#pragma unroll
    for (int ct = 0; ct < 4; ++ct) {
      int col = n0 + ct * 16 + ln;
      out[row * 512 + col] = x[row * 512 + col] + acc[ct][j];
    }
  }
}

// ---------------------------------------------------------------------------
extern "C" void kernel_launch(void* const* d_in, const int* in_sizes, int n_in,
                              void* d_out, int out_size, void* d_ws,
                              size_t ws_size, hipStream_t stream) {
  (void)in_sizes; (void)n_in; (void)out_size; (void)ws_size;
  const float* x = (const float*)d_in[0];
  const float* cosb = (const float*)d_in[1];
  const float* sinb = (const float*)d_in[2];
  const float* Wq = (const float*)d_in[3];
  const float* Wk = (const float*)d_in[4];
  const float* Wv = (const float*)d_in[5];
  const float* Wo = (const float*)d_in[6];
  float* out = (float*)d_out;

  float* ws = (float*)d_ws;
  float* Q = ws;                        // 1,048,576 f
  float* Kt = Q + (size_t)1048576;      //   524,288 f
  float* Vt = Kt + (size_t)524288;      //   524,288 f
  float* Yb = Vt + (size_t)524288;      // 1,048,576 f
  float* invs = Yb + (size_t)1048576;   //    16,384 f
  float* part = invs + (size_t)16384;   //   262,144 f
  u16* A = (u16*)(part + 262144);       // 16,777,216 u16 = 32 MB
  u16* WtH = A + (size_t)16777216;      //   524,288 u16
  u16* WtL = WtH + (size_t)524288;
  u16* WotH = WtL + (size_t)524288;     //   262,144 u16
  u16* WotL = WotH + (size_t)262144;    // total ~49 MB

  prep_kernel<<<dim3(8, 24), 256, 0, stream>>>(Wq, Wk, Wv, Wo, WtH, WtL, WotH,
                                               WotL);
  qkv_mfma_kernel<<<dim3(16, 16), 512, 0, stream>>>(x, WtH, WtL, cosb, sinb,
                                                    Q, Kt, Vt);
  logits_mfma_kernel<<<dim3(16, 136), 256, 0, stream>>>(Q, Kt, A, part);
  diaginv_kernel<<<dim3(16, 16), 64, 0, stream>>>(A, part, invs);
  solve_mfma_kernel<<<dim3(16, 4), 1024, 0, stream>>>(A, invs, Vt, Yb);
  out_proj_mfma_kernel<<<dim3(8, 16), 512, 0, stream>>>(Yb, WotH, WotL, x, out);
}

// Round 24
// 132.085 us; speedup vs baseline: 1.0321x; 1.0321x over previous
//
#include <hip/hip_runtime.h>
#include <cmath>

#define TT 1024
#define HH 8
#define KVHN 4

typedef unsigned short u16;
typedef __attribute__((ext_vector_type(8))) short bf16x8;
typedef __attribute__((ext_vector_type(4))) float f32x4;

#define MFMA(a, b, c) __builtin_amdgcn_mfma_f32_16x16x32_bf16(a, b, c, 0, 0, 0)

__device__ __forceinline__ float bflo(unsigned u) { return __uint_as_float(u << 16); }
__device__ __forceinline__ float bfhi(unsigned u) { return __uint_as_float(u & 0xffff0000u); }
__device__ __forceinline__ u16 bfr(float f) {
  unsigned u = __float_as_uint(f);
  return (u16)((u + 0x7fffu + ((u >> 16) & 1u)) >> 16);
}
__device__ __forceinline__ float hpart(u16 h) {
  return __uint_as_float((unsigned)h << 16);
}

__device__ __forceinline__ bf16x8 ld8_g(const u16* __restrict__ p) {
  uint4 v = *reinterpret_cast<const uint4*>(p);
  return __builtin_bit_cast(bf16x8, v);
}
__device__ __forceinline__ bf16x8 ld8_lds(const u16* s, int col, int k8) {
  const uint4* p = reinterpret_cast<const uint4*>(s);
  return __builtin_bit_cast(bf16x8, p[col * 8 + (k8 ^ (col & 7))]);
}
__device__ __forceinline__ void st_split_lds(u16* sh, u16* sl, int col, int r0,
                                             f32x4 v) {
  u16 hh[4], ll[4];
#pragma unroll
  for (int j = 0; j < 4; ++j) {
    u16 hb = bfr(v[j]);
    hh[j] = hb;
    ll[j] = bfr(v[j] - hpart(hb));
  }
  uint2 ph, pl;
  ph.x = (unsigned)hh[0] | ((unsigned)hh[1] << 16);
  ph.y = (unsigned)hh[2] | ((unsigned)hh[3] << 16);
  pl.x = (unsigned)ll[0] | ((unsigned)ll[1] << 16);
  pl.y = (unsigned)ll[2] | ((unsigned)ll[3] << 16);
  int idx = col * 64 + (((r0 >> 3) ^ (col & 7)) << 3) + (r0 & 7);
  *reinterpret_cast<uint2*>(sh + idx) = ph;
  *reinterpret_cast<uint2*>(sl + idx) = pl;
}
// split 8 f32 (two float4) into hi/lo bf16x8
__device__ __forceinline__ void cvt8v(float4 a, float4 b, bf16x8& h, bf16x8& l) {
  float v[8] = {a.x, a.y, a.z, a.w, b.x, b.y, b.z, b.w};
  unsigned hh[8], ll[8];
#pragma unroll
  for (int j = 0; j < 8; ++j) {
    u16 hb = bfr(v[j]);
    hh[j] = hb;
    ll[j] = bfr(v[j] - hpart(hb));
  }
  uint4 H, L;
  H.x = hh[0] | (hh[1] << 16); H.y = hh[2] | (hh[3] << 16);
  H.z = hh[4] | (hh[5] << 16); H.w = hh[6] | (hh[7] << 16);
  L.x = ll[0] | (ll[1] << 16); L.y = ll[2] | (ll[3] << 16);
  L.z = ll[4] | (ll[5] << 16); L.w = ll[6] | (ll[7] << 16);
  h = __builtin_bit_cast(bf16x8, H);
  l = __builtin_bit_cast(bf16x8, L);
}
// load 8 consecutive f32, split into hi/lo bf16x8
__device__ __forceinline__ void cvt8(const float* __restrict__ p, bf16x8& h,
                                     bf16x8& l) {
  float4 a = *reinterpret_cast<const float4*>(p);
  float4 b = *reinterpret_cast<const float4*>(p + 4);
  cvt8v(a, b, h, l);
}

// ---------------------------------------------------------------------------
// K0: prep — transpose+split WEIGHTS ONLY to bf16 hi/lo [n][k]. Grid (8, 24).
// ---------------------------------------------------------------------------
__global__ __launch_bounds__(256) void prep_kernel(
    const float* __restrict__ Wq, const float* __restrict__ Wk,
    const float* __restrict__ Wv, const float* __restrict__ Wo,
    u16* __restrict__ WtH, u16* __restrict__ WtL, u16* __restrict__ WotH,
    u16* __restrict__ WotL) {
  const int kt = blockIdx.x, nt = blockIdx.y;
  const int tid = threadIdx.x;
  const int k0 = kt * 64;

  const float* Wsel;
  int wstride, wc0;
  u16 *oh, *ol;
  if (nt < 16) {
    if (nt < 8) { Wsel = Wq; wstride = 512; wc0 = nt * 64; }
    else if (nt < 12) { Wsel = Wk; wstride = 256; wc0 = (nt - 8) * 64; }
    else { Wsel = Wv; wstride = 256; wc0 = (nt - 12) * 64; }
    oh = WtH + (size_t)(nt * 64) * 512;
    ol = WtL + (size_t)(nt * 64) * 512;
  } else {
    Wsel = Wo; wstride = 512; wc0 = (nt - 16) * 64;
    oh = WotH + (size_t)((nt - 16) * 64) * 512;
    ol = WotL + (size_t)((nt - 16) * 64) * 512;
  }

  __shared__ float Ws[64][68];
#pragma unroll
  for (int m = 0; m < 4; ++m) {
    int f = m * 256 + tid;
    int rr = f >> 4, dc = (f & 15) * 4;
    *reinterpret_cast<float4*>(&Ws[rr][dc]) =
        *reinterpret_cast<const float4*>(Wsel + (size_t)(k0 + rr) * wstride + wc0 + dc);
  }
  __syncthreads();

  const int nr = tid >> 2, kc0 = (tid & 3) * 16;
  u16* dh = oh + (size_t)nr * 512 + k0 + kc0;
  u16* dl = ol + (size_t)nr * 512 + k0 + kc0;
#pragma unroll
  for (int i = 0; i < 16; i += 2) {
    float a = Ws[kc0 + i][nr], b = Ws[kc0 + i + 1][nr];
    u16 ha = bfr(a), hb2 = bfr(b);
    u16 la = bfr(a - hpart(ha));
    u16 lb = bfr(b - hpart(hb2));
    *reinterpret_cast<unsigned*>(dh + i) = (unsigned)ha | ((unsigned)hb2 << 16);
    *reinterpret_cast<unsigned*>(dl + i) = (unsigned)la | ((unsigned)lb << 16);
  }
}

// ---------------------------------------------------------------------------
// K1: QKV via MFMA, 128x64 LDS-staged tile; x f32 -> hi/lo DURING staging.
// Grid (16 cy, 16 rt), 512 thr. In-register RoPE. (round-23 version)
// ---------------------------------------------------------------------------
__global__ __launch_bounds__(512) void qkv_mfma_kernel(
    const float* __restrict__ x, const u16* __restrict__ WtH,
    const u16* __restrict__ WtL, const float* __restrict__ cosb,
    const float* __restrict__ sinb, float* __restrict__ Q,
    float* __restrict__ Kt, float* __restrict__ Vt) {
  const int cy = blockIdx.x, rt = blockIdx.y;
  const int tid = threadIdx.x;
  const int lane = tid & 63, w = tid >> 6;
  const int ln = lane & 15, kg = lane >> 4;
  const int n0 = cy * 64, m0 = rt * 128;

  __shared__ u16 XHs[128 * 64], XLs[128 * 64];
  __shared__ u16 WHs[64 * 64], WLs[64 * 64];

  auto LD8T = [&](const u16* s, int row, int k8) {
    return __builtin_bit_cast(
        bf16x8, reinterpret_cast<const uint4*>(s)[row * 8 + (k8 ^ (row & 7))]);
  };

  f32x4 acc[4];
#pragma unroll
  for (int ct = 0; ct < 4; ++ct) acc[ct] = {0.f, 0.f, 0.f, 0.f};

  for (int c = 0; c < 8; ++c) {
    const int k0 = c * 64;
    __syncthreads();
#pragma unroll
    for (int m = 0; m < 2; ++m) {
      int f = m * 512 + tid;
      int srow = f >> 3, sk8 = f & 7;
      int slot = srow * 8 + (sk8 ^ (srow & 7));
      const float* xp = x + (size_t)(m0 + srow) * 512 + k0 + sk8 * 8;
      bf16x8 h, l;
      cvt8(xp, h, l);
      reinterpret_cast<uint4*>(XHs)[slot] = __builtin_bit_cast(uint4, h);
      reinterpret_cast<uint4*>(XLs)[slot] = __builtin_bit_cast(uint4, l);
    }
    {
      int wrow = tid >> 3, wk8 = tid & 7;
      int slot = wrow * 8 + (wk8 ^ (wrow & 7));
      reinterpret_cast<uint4*>(WHs)[slot] = *reinterpret_cast<const uint4*>(
          WtH + (size_t)(n0 + wrow) * 512 + k0 + wk8 * 8);
      reinterpret_cast<uint4*>(WLs)[slot] = *reinterpret_cast<const uint4*>(
          WtL + (size_t)(n0 + wrow) * 512 + k0 + wk8 * 8);
    }
    __syncthreads();

#pragma unroll
    for (int win = 0; win < 2; ++win) {
      int k8a = win * 4 + kg;
      bf16x8 ah = LD8T(XHs, w * 16 + ln, k8a);
      bf16x8 al = LD8T(XLs, w * 16 + ln, k8a);
#pragma unroll
      for (int ct = 0; ct < 4; ++ct) {
        bf16x8 bh = LD8T(WHs, ct * 16 + ln, k8a);
        bf16x8 bl = LD8T(WLs, ct * 16 + ln, k8a);
        acc[ct] = MFMA(ah, bh, acc[ct]);
        acc[ct] = MFMA(al, bh, acc[ct]);
        acc[ct] = MFMA(ah, bl, acc[ct]);
      }
    }
  }

  const int trow0 = m0 + w * 16 + kg * 4;
  if (cy < 12) {
#pragma unroll
    for (int j = 0; j < 4; ++j) {
      int row = trow0 + j, b = row >> 10, t = row & 1023;
      float* OP;
      size_t base;
      if (cy < 8) {
        OP = Q;
        base = ((size_t)(b * HH + cy) * TT + t) * 64;
      } else {
        OP = Kt;
        base = ((size_t)(b * KVHN + (cy - 8)) * TT + t) * 64;
      }
#pragma unroll
      for (int ct = 0; ct < 2; ++ct) {
        int dd = ct * 16 + ln;
        float cc = cosb[t * 32 + dd], ss = sinb[t * 32 + dd];
        float v1 = acc[ct][j], v2 = acc[ct + 2][j];
        OP[base + dd] = v1 * cc + v2 * ss;
        OP[base + 32 + dd] = v2 * cc - v1 * ss;
      }
    }
  } else {
#pragma unroll
    for (int j = 0; j < 4; ++j) {
      int row = trow0 + j, b = row >> 10, t = row & 1023;
      size_t base = ((size_t)(b * KVHN + (cy - 12)) * TT + t) * 64;
#pragma unroll
      for (int ct = 0; ct < 4; ++ct) Vt[base + ct * 16 + ln] = acc[ct][j];
    }
  }
}

// ---------------------------------------------------------------------------
// K2: MFMA causal logits + exp -> A (bf16). Grid (16 sys, 136 n). (r20)
// ---------------------------------------------------------------------------
__global__ __launch_bounds__(256) void logits_mfma_kernel(
    const float* __restrict__ Q, const float* __restrict__ Kt,
    u16* __restrict__ A, float* __restrict__ part) {
  const int sys = blockIdx.x, n = blockIdx.y;
  int it = 0;
  while ((it + 1) * (it + 2) / 2 <= n) ++it;
  const int jt = n - it * (it + 1) / 2;
  const int b = sys >> 3, kvh = (sys & 7) >> 1;
  const int tid = threadIdx.x;
  const int lane = tid & 63, w = tid >> 6;
  const int ln = lane & 15, kg = lane >> 4;
  const int m0 = w * 16;

  const float* Qr = Q + ((size_t)sys * TT + it * 64 + m0 + ln) * 64;
  const float* Kb = Kt + ((size_t)(b * KVHN + kvh) * TT + jt * 64) * 64;
  u16* Aout = A + ((size_t)sys << 20);

  bf16x8 qh0, ql0, qh1, ql1;
  cvt8(Qr + kg * 8, qh0, ql0);
  cvt8(Qr + 32 + kg * 8, qh1, ql1);

  f32x4 acc[4];
#pragma unroll
  for (int ct = 0; ct < 4; ++ct) {
    const float* Kr = Kb + (size_t)(ct * 16 + ln) * 64;
    bf16x8 kh0, kl0, kh1, kl1;
    cvt8(Kr + kg * 8, kh0, kl0);
    cvt8(Kr + 32 + kg * 8, kh1, kl1);
    f32x4 a = {0.f, 0.f, 0.f, 0.f};
    a = MFMA(qh0, kh0, a);
    a = MFMA(qh1, kh1, a);
    a = MFMA(qh0, kl0, a);
    a = MFMA(qh1, kl1, a);
    a = MFMA(ql0, kh0, a);
    a = MFMA(ql1, kh1, a);
    acc[ct] = a;
  }

  const int grow0 = it * 64 + m0;
  const bool full = (jt < it);
  float s[4] = {0.f, 0.f, 0.f, 0.f};
#pragma unroll
  for (int ct = 0; ct < 4; ++ct) {
    int col = jt * 64 + ct * 16 + ln;
#pragma unroll
    for (int j = 0; j < 4; ++j) {
      int row = grow0 + kg * 4 + j;
      float e = (full || col <= row) ? __expf(acc[ct][j] * 0.125f) : 0.f;
      s[j] += e;
      Aout[(size_t)row * 1024 + col] = bfr(e);
    }
  }

#pragma unroll
  for (int off = 1; off < 16; off <<= 1) {
#pragma unroll
    for (int j = 0; j < 4; ++j) s[j] += __shfl_xor(s[j], off);
  }
  if (ln == 0) {
#pragma unroll
    for (int j = 0; j < 4; ++j)
      part[((size_t)(sys * 16 + jt)) * 1024 + grow0 + kg * 4 + j] = s[j];
  }
}

// ---------------------------------------------------------------------------
// K3a: barrier-free one-wave diag-block inversion. (round-15 proven)
// ---------------------------------------------------------------------------
__global__ __launch_bounds__(64) void diaginv_kernel(
    u16* __restrict__ A, const float* __restrict__ part,
    float* __restrict__ invs) {
  const int k = blockIdx.x, sys = blockIdx.y;
  const int c = threadIdx.x;

  u16* Ab = A + ((size_t)sys << 20) + (size_t)(k * 64) * 1024 + k * 64;

  __shared__ float MsT[64][68];
  __shared__ float dv[64];

  {
    const int r = c;
    float row[64];
#pragma unroll
    for (int m8 = 0; m8 < 8; ++m8) {
      uint4 v = *reinterpret_cast<const uint4*>(Ab + (size_t)r * 1024 + m8 * 8);
      row[m8 * 8 + 0] = bflo(v.x); row[m8 * 8 + 1] = bfhi(v.x);
      row[m8 * 8 + 2] = bflo(v.y); row[m8 * 8 + 3] = bfhi(v.y);
      row[m8 * 8 + 4] = bflo(v.z); row[m8 * 8 + 5] = bfhi(v.z);
      row[m8 * 8 + 6] = bflo(v.w); row[m8 * 8 + 7] = bfhi(v.w);
    }
    float s = 0.f;
    for (int jt = 0; jt <= k; ++jt)
      s += part[((size_t)(sys * 16 + jt)) * 1024 + k * 64 + r];
    float svr = 1.0f / s;
    invs[sys * 1024 + k * 64 + r] = svr;
    dv[r] = 1.0f / (1.0f + svr * row[r]);
#pragma unroll
    for (int j = 0; j < 64; ++j) MsT[j][r] = svr * row[j];
  }
  __syncthreads();

  float dvr[64];
#pragma unroll
  for (int q = 0; q < 64; ++q) dvr[q] = dv[q];

  float w[64], acc[64];
#pragma unroll
  for (int r = 0; r < 64; ++r) acc[r] = 0.f;

#pragma unroll
  for (int r = 0; r < 64; ++r) {
    float wr = ((r == c) ? 1.0f : 0.0f) - acc[r];
    wr *= dvr[r];
    w[r] = wr;
#pragma unroll
    for (int q = (r + 1) >> 2; q < 16; ++q) {
      float4 m4 = *reinterpret_cast<const float4*>(&MsT[r][q * 4]);
      acc[q * 4 + 0] += m4.x * wr;
      acc[q * 4 + 1] += m4.y * wr;
      acc[q * 4 + 2] += m4.z * wr;
      acc[q * 4 + 3] += m4.w * wr;
    }
  }

#pragma unroll
  for (int r = 0; r < 64; ++r) Ab[(size_t)r * 1024 + c] = bfr(w[r]);
}

// ---------------------------------------------------------------------------
// K3b: right-looking MFMA solve — EXACT round-16/22 version (proven 47.5 us).
// Yg stores inside phase 2 (before B2). FROZEN.
// ---------------------------------------------------------------------------
__global__ __launch_bounds__(1024) void solve_mfma_kernel(
    const u16* __restrict__ A, const float* __restrict__ invs,
    const float* __restrict__ Vt, float* __restrict__ Yout) {
  const int sys = blockIdx.x, cq = blockIdx.y;
  const int bb = sys >> 3, kvh = (sys & 7) >> 1;
  const int c0 = cq * 16;
  const int tid = threadIdx.x;
  const int lane = tid & 63, w = tid >> 6;
  const int ln = lane & 15, kg = lane >> 4;

  const u16* Ab = A + ((size_t)sys << 20);
  const float* Vb = Vt + ((size_t)(bb * KVHN + kvh) * TT) * 64;
  float* Yg = Yout + (size_t)sys * TT * 64;

  __shared__ float U[16][1031];
  __shared__ u16 yh[16 * 64], yl[16 * 64];
  __shared__ u16 uh[16 * 64], ul[16 * 64];

  {
    float* Uf = &U[0][0];
    for (int i = tid; i < 16 * 1031; i += 1024) Uf[i] = 0.f;
  }
  __syncthreads();

  for (int k = 0; k < 16; ++k) {
    const int rg0 = k * 64;

    uint4 pm0 = {}, pm1 = {};
    f32x4 pv = {0.f, 0.f, 0.f, 0.f}, psi = {0.f, 0.f, 0.f, 0.f};
    if (w < 4) {
      const u16* mrow = Ab + (size_t)(rg0 + w * 16 + ln) * 1024 + rg0;
      pm0 = *reinterpret_cast<const uint4*>(mrow + kg * 8);
      pm1 = *reinterpret_cast<const uint4*>(mrow + 32 + kg * 8);
#pragma unroll
      for (int j = 0; j < 4; ++j) {
        int gr = rg0 + w * 16 + kg * 4 + j;
        pv[j] = Vb[(size_t)gr * 64 + c0 + ln];
        psi[j] = invs[sys * 1024 + gr];
      }
    }
    const int nu = (15 - k) * 4;
    uint4 pa0[4], pa1[4];
    bool val[4];
#pragma unroll
    for (int t = 0; t < 4; ++t) {
      int un = w + 16 * t;
      val[t] = un < nu;
      if (val[t]) {
        const u16* ar =
            Ab + (size_t)((k + 1 + (un >> 2)) * 64 + (un & 3) * 16 + ln) * 1024 +
            rg0;
        pa0[t] = *reinterpret_cast<const uint4*>(ar + kg * 8);
        pa1[t] = *reinterpret_cast<const uint4*>(ar + 32 + kg * 8);
      }
    }
    __builtin_amdgcn_sched_barrier(0);  // pin: loads issue BEFORE phases

    if (w < 4) {
      f32x4 u;
#pragma unroll
      for (int j = 0; j < 4; ++j) {
        int gr = rg0 + w * 16 + kg * 4 + j;
        u[j] = pv[j] - psi[j] * U[ln][gr];
      }
      st_split_lds(uh, ul, ln, w * 16 + kg * 4, u);
    }
    __syncthreads();

    if (w < 4) {
      bf16x8 ma0 = __builtin_bit_cast(bf16x8, pm0);
      bf16x8 ma1 = __builtin_bit_cast(bf16x8, pm1);
      f32x4 y = {0.f, 0.f, 0.f, 0.f};
      y = MFMA(ma0, ld8_lds(uh, ln, kg), y);
      y = MFMA(ma1, ld8_lds(uh, ln, 4 + kg), y);
      y = MFMA(ma0, ld8_lds(ul, ln, kg), y);
      y = MFMA(ma1, ld8_lds(ul, ln, 4 + kg), y);
#pragma unroll
      for (int j = 0; j < 4; ++j)
        Yg[(size_t)(rg0 + w * 16 + kg * 4 + j) * 64 + c0 + ln] = y[j];
      st_split_lds(yh, yl, ln, w * 16 + kg * 4, y);
    }
    __syncthreads();

#pragma unroll
    for (int t = 0; t < 4; ++t) {
      if (val[t]) {
        int un = w + 16 * t;
        int rb = (k + 1 + (un >> 2)) * 64 + (un & 3) * 16 + kg * 4;
        bf16x8 a0 = __builtin_bit_cast(bf16x8, pa0[t]);
        bf16x8 a1 = __builtin_bit_cast(bf16x8, pa1[t]);
        f32x4 s = {0.f, 0.f, 0.f, 0.f};
        s = MFMA(a0, ld8_lds(yh, ln, kg), s);
        s = MFMA(a1, ld8_lds(yh, ln, 4 + kg), s);
        s = MFMA(a0, ld8_lds(yl, ln, kg), s);
        s = MFMA(a1, ld8_lds(yl, ln, 4 + kg), s);
#pragma unroll
        for (int j = 0; j < 4; ++j) U[ln][rb + j] += s[j];
      }
    }
    __syncthreads();
  }
}

// ---------------------------------------------------------------------------
// K4: out = x + Y2d @ Wo via MFMA, 128x64 LDS-staged tile. (round-22 proven)
// ---------------------------------------------------------------------------
__global__ __launch_bounds__(512) void out_proj_mfma_kernel(
    const float* __restrict__ Y, const u16* __restrict__ WotH,
    const u16* __restrict__ WotL, const float* __restrict__ x,
    float* __restrict__ out) {
  const int cy = blockIdx.x, rt = blockIdx.y;
  const int tid = threadIdx.x;
  const int lane = tid & 63, w = tid >> 6;
  const int ln = lane & 15, kg = lane >> 4;
  const int n0 = cy * 64, m0 = rt * 128;

  __shared__ u16 YHs[128 * 64], YLs[128 * 64];
  __shared__ u16 WHs[64 * 64], WLs[64 * 64];

  auto LD8T = [&](const u16* s, int row, int k8) {
    return __builtin_bit_cast(
        bf16x8, reinterpret_cast<const uint4*>(s)[row * 8 + (k8 ^ (row & 7))]);
  };

  f32x4 acc[4];
#pragma unroll
  for (int ct = 0; ct < 4; ++ct) acc[ct] = {0.f, 0.f, 0.f, 0.f};

  for (int c = 0; c < 8; ++c) {
    const int k0 = c * 64;
    __syncthreads();
#pragma unroll
    for (int m = 0; m < 2; ++m) {
      int f = m * 512 + tid;
      int srow = f >> 3, sk8 = f & 7;
      int slot = srow * 8 + (sk8 ^ (srow & 7));
      int row = m0 + srow, b = row >> 10, t = row & 1023;
      const float* yp = Y + ((size_t)(b * HH + c) * TT + t) * 64 + sk8 * 8;
      bf16x8 h, l;
      cvt8(yp, h, l);
      reinterpret_cast<uint4*>(YHs)[slot] = __builtin_bit_cast(uint4, h);
      reinterpret_cast<uint4*>(YLs)[slot] = __builtin_bit_cast(uint4, l);
    }
    {
      int wrow = tid >> 3, wk8 = tid & 7;
      int slot = wrow * 8 + (wk8 ^ (wrow & 7));
      reinterpret_cast<uint4*>(WHs)[slot] = *reinterpret_cast<const uint4*>(
          WotH + (size_t)(n0 + wrow) * 512 + k0 + wk8 * 8);
      reinterpret_cast<uint4*>(WLs)[slot] = *reinterpret_cast<const uint4*>(
          WotL + (size_t)(n0 + wrow) * 512 + k0 + wk8 * 8);
    }
    __syncthreads();

#pragma unroll
    for (int win = 0; win < 2; ++win) {
      int k8a = win * 4 + kg;
      bf16x8 ah = LD8T(YHs, w * 16 + ln, k8a);
      bf16x8 al = LD8T(YLs, w * 16 + ln, k8a);
#pragma unroll
      for (int ct = 0; ct < 4; ++ct) {
        bf16x8 bh = LD8T(WHs, ct * 16 + ln, k8a);
        bf16x8 bl = LD8T(WLs, ct * 16 + ln, k8a);
        acc[ct] = MFMA(ah, bh, acc[ct]);
        acc[ct] = MFMA(al, bh, acc[ct]);
        acc[ct] = MFMA(ah, bl, acc[ct]);
      }
    }
  }

  const int trow0 = m0 + w * 16 + kg * 4;
#pragma unroll
  for (int j = 0; j < 4; ++j) {
    size_t row = (size_t)(trow0 + j);
#pragma unroll
    for (int ct = 0; ct < 4; ++ct) {
      int col = n0 + ct * 16 + ln;
      out[row * 512 + col] = x[row * 512 + col] + acc[ct][j];
    }
  }
}

// ---------------------------------------------------------------------------
extern "C" void kernel_launch(void* const* d_in, const int* in_sizes, int n_in,
                              void* d_out, int out_size, void* d_ws,
                              size_t ws_size, hipStream_t stream) {
  (void)in_sizes; (void)n_in; (void)out_size; (void)ws_size;
  const float* x = (const float*)d_in[0];
  const float* cosb = (const float*)d_in[1];
  const float* sinb = (const float*)d_in[2];
  const float* Wq = (const float*)d_in[3];
  const float* Wk = (const float*)d_in[4];
  const float* Wv = (const float*)d_in[5];
  const float* Wo = (const float*)d_in[6];
  float* out = (float*)d_out;

  float* ws = (float*)d_ws;
  float* Q = ws;                        // 1,048,576 f
  float* Kt = Q + (size_t)1048576;      //   524,288 f
  float* Vt = Kt + (size_t)524288;      //   524,288 f
  float* Yb = Vt + (size_t)524288;      // 1,048,576 f
  float* invs = Yb + (size_t)1048576;   //    16,384 f
  float* part = invs + (size_t)16384;   //   262,144 f
  u16* A = (u16*)(part + 262144);       // 16,777,216 u16 = 32 MB
  u16* WtH = A + (size_t)16777216;      //   524,288 u16
  u16* WtL = WtH + (size_t)524288;
  u16* WotH = WtL + (size_t)524288;     //   262,144 u16
  u16* WotL = WotH + (size_t)262144;    // total ~49 MB

  prep_kernel<<<dim3(8, 24), 256, 0, stream>>>(Wq, Wk, Wv, Wo, WtH, WtL, WotH,
                                               WotL);
  qkv_mfma_kernel<<<dim3(16, 16), 512, 0, stream>>>(x, WtH, WtL, cosb, sinb,
                                                    Q, Kt, Vt);
  logits_mfma_kernel<<<dim3(16, 136), 256, 0, stream>>>(Q, Kt, A, part);
  diaginv_kernel<<<dim3(16, 16), 64, 0, stream>>>(A, part, invs);
  solve_mfma_kernel<<<dim3(16, 4), 1024, 0, stream>>>(A, invs, Vt, Yb);
  out_proj_mfma_kernel<<<dim3(8, 16), 512, 0, stream>>>(Yb, WotH, WotL, x, out);
}

// Round 25
// 129.737 us; speedup vs baseline: 1.0508x; 1.0181x over previous
//
#include <hip/hip_runtime.h>
#include <cmath>

#define TT 1024
#define HH 8
#define KVHN 4

typedef unsigned short u16;
typedef __attribute__((ext_vector_type(8))) short bf16x8;
typedef __attribute__((ext_vector_type(4))) float f32x4;

#define MFMA(a, b, c) __builtin_amdgcn_mfma_f32_16x16x32_bf16(a, b, c, 0, 0, 0)

__device__ __forceinline__ float bflo(unsigned u) { return __uint_as_float(u << 16); }
__device__ __forceinline__ float bfhi(unsigned u) { return __uint_as_float(u & 0xffff0000u); }
__device__ __forceinline__ u16 bfr(float f) {
  unsigned u = __float_as_uint(f);
  return (u16)((u + 0x7fffu + ((u >> 16) & 1u)) >> 16);
}
__device__ __forceinline__ float hpart(u16 h) {
  return __uint_as_float((unsigned)h << 16);
}

__device__ __forceinline__ bf16x8 ld8_g(const u16* __restrict__ p) {
  uint4 v = *reinterpret_cast<const uint4*>(p);
  return __builtin_bit_cast(bf16x8, v);
}
__device__ __forceinline__ bf16x8 ld8_lds(const u16* s, int col, int k8) {
  const uint4* p = reinterpret_cast<const uint4*>(s);
  return __builtin_bit_cast(bf16x8, p[col * 8 + (k8 ^ (col & 7))]);
}
__device__ __forceinline__ void st_split_lds(u16* sh, u16* sl, int col, int r0,
                                             f32x4 v) {
  u16 hh[4], ll[4];
#pragma unroll
  for (int j = 0; j < 4; ++j) {
    u16 hb = bfr(v[j]);
    hh[j] = hb;
    ll[j] = bfr(v[j] - hpart(hb));
  }
  uint2 ph, pl;
  ph.x = (unsigned)hh[0] | ((unsigned)hh[1] << 16);
  ph.y = (unsigned)hh[2] | ((unsigned)hh[3] << 16);
  pl.x = (unsigned)ll[0] | ((unsigned)ll[1] << 16);
  pl.y = (unsigned)ll[2] | ((unsigned)ll[3] << 16);
  int idx = col * 64 + (((r0 >> 3) ^ (col & 7)) << 3) + (r0 & 7);
  *reinterpret_cast<uint2*>(sh + idx) = ph;
  *reinterpret_cast<uint2*>(sl + idx) = pl;
}
// split 8 f32 (two float4) into hi/lo bf16x8
__device__ __forceinline__ void cvt8v(float4 a, float4 b, bf16x8& h, bf16x8& l) {
  float v[8] = {a.x, a.y, a.z, a.w, b.x, b.y, b.z, b.w};
  unsigned hh[8], ll[8];
#pragma unroll
  for (int j = 0; j < 8; ++j) {
    u16 hb = bfr(v[j]);
    hh[j] = hb;
    ll[j] = bfr(v[j] - hpart(hb));
  }
  uint4 H, L;
  H.x = hh[0] | (hh[1] << 16); H.y = hh[2] | (hh[3] << 16);
  H.z = hh[4] | (hh[5] << 16); H.w = hh[6] | (hh[7] << 16);
  L.x = ll[0] | (ll[1] << 16); L.y = ll[2] | (ll[3] << 16);
  L.z = ll[4] | (ll[5] << 16); L.w = ll[6] | (ll[7] << 16);
  h = __builtin_bit_cast(bf16x8, H);
  l = __builtin_bit_cast(bf16x8, L);
}
// load 8 consecutive f32, split into hi/lo bf16x8
__device__ __forceinline__ void cvt8(const float* __restrict__ p, bf16x8& h,
                                     bf16x8& l) {
  float4 a = *reinterpret_cast<const float4*>(p);
  float4 b = *reinterpret_cast<const float4*>(p + 4);
  cvt8v(a, b, h, l);
}

// ---------------------------------------------------------------------------
// K0: prep — transpose+split weights to bf16 hi/lo [n][k]; convert x to hi/lo
// ONCE (amortized; fusing into qkv was 16x-redundant and regressed).
// Grid (8, 56): nt<16 Wqkv, nt<24 Wo, else x rows.
// ---------------------------------------------------------------------------
__global__ __launch_bounds__(256) void prep_kernel(
    const float* __restrict__ x, const float* __restrict__ Wq,
    const float* __restrict__ Wk, const float* __restrict__ Wv,
    const float* __restrict__ Wo, u16* __restrict__ WtH, u16* __restrict__ WtL,
    u16* __restrict__ WotH, u16* __restrict__ WotL, u16* __restrict__ Xh,
    u16* __restrict__ Xl) {
  const int kt = blockIdx.x, nt = blockIdx.y;
  const int tid = threadIdx.x;
  const int k0 = kt * 64;

  if (nt >= 24) {
    const int r0 = (nt - 24) * 64;
    const int rr = tid >> 2, kc0 = (tid & 3) * 16;
    const float* src = x + (size_t)(r0 + rr) * 512 + k0 + kc0;
    u16* dh = Xh + (size_t)(r0 + rr) * 512 + k0 + kc0;
    u16* dl = Xl + (size_t)(r0 + rr) * 512 + k0 + kc0;
#pragma unroll
    for (int m = 0; m < 4; ++m) {
      float4 v = *reinterpret_cast<const float4*>(src + m * 4);
      float vv[4] = {v.x, v.y, v.z, v.w};
      u16 hh[4], ll[4];
#pragma unroll
      for (int j = 0; j < 4; ++j) {
        u16 hb = bfr(vv[j]);
        hh[j] = hb;
        ll[j] = bfr(vv[j] - hpart(hb));
      }
      uint2 ph, pl;
      ph.x = (unsigned)hh[0] | ((unsigned)hh[1] << 16);
      ph.y = (unsigned)hh[2] | ((unsigned)hh[3] << 16);
      pl.x = (unsigned)ll[0] | ((unsigned)ll[1] << 16);
      pl.y = (unsigned)ll[2] | ((unsigned)ll[3] << 16);
      *reinterpret_cast<uint2*>(dh + m * 4) = ph;
      *reinterpret_cast<uint2*>(dl + m * 4) = pl;
    }
    return;
  }

  const float* Wsel;
  int wstride, wc0;
  u16 *oh, *ol;
  if (nt < 16) {
    if (nt < 8) { Wsel = Wq; wstride = 512; wc0 = nt * 64; }
    else if (nt < 12) { Wsel = Wk; wstride = 256; wc0 = (nt - 8) * 64; }
    else { Wsel = Wv; wstride = 256; wc0 = (nt - 12) * 64; }
    oh = WtH + (size_t)(nt * 64) * 512;
    ol = WtL + (size_t)(nt * 64) * 512;
  } else {
    Wsel = Wo; wstride = 512; wc0 = (nt - 16) * 64;
    oh = WotH + (size_t)((nt - 16) * 64) * 512;
    ol = WotL + (size_t)((nt - 16) * 64) * 512;
  }

  __shared__ float Ws[64][68];
#pragma unroll
  for (int m = 0; m < 4; ++m) {
    int f = m * 256 + tid;
    int rr = f >> 4, dc = (f & 15) * 4;
    *reinterpret_cast<float4*>(&Ws[rr][dc]) =
        *reinterpret_cast<const float4*>(Wsel + (size_t)(k0 + rr) * wstride + wc0 + dc);
  }
  __syncthreads();

  const int nr = tid >> 2, kc0 = (tid & 3) * 16;
  u16* dh = oh + (size_t)nr * 512 + k0 + kc0;
  u16* dl = ol + (size_t)nr * 512 + k0 + kc0;
#pragma unroll
  for (int i = 0; i < 16; i += 2) {
    float a = Ws[kc0 + i][nr], b = Ws[kc0 + i + 1][nr];
    u16 ha = bfr(a), hb2 = bfr(b);
    u16 la = bfr(a - hpart(ha));
    u16 lb = bfr(b - hpart(hb2));
    *reinterpret_cast<unsigned*>(dh + i) = (unsigned)ha | ((unsigned)hb2 << 16);
    *reinterpret_cast<unsigned*>(dl + i) = (unsigned)la | ((unsigned)lb << 16);
  }
}

// ---------------------------------------------------------------------------
// K1: QKV via MFMA, 128x64 LDS-staged tile. (round-21 proven, reads Xh/Xl)
// Grid (16 cy, 16 rt), 512 thr (8 waves x 16 rows). In-register RoPE.
// ---------------------------------------------------------------------------
__global__ __launch_bounds__(512) void qkv_mfma_kernel(
    const u16* __restrict__ Xh, const u16* __restrict__ Xl,
    const u16* __restrict__ WtH, const u16* __restrict__ WtL,
    const float* __restrict__ cosb, const float* __restrict__ sinb,
    float* __restrict__ Q, float* __restrict__ Kt, float* __restrict__ Vt) {
  const int cy = blockIdx.x, rt = blockIdx.y;
  const int tid = threadIdx.x;
  const int lane = tid & 63, w = tid >> 6;
  const int ln = lane & 15, kg = lane >> 4;
  const int n0 = cy * 64, m0 = rt * 128;

  __shared__ u16 XHs[128 * 64], XLs[128 * 64];
  __shared__ u16 WHs[64 * 64], WLs[64 * 64];

  auto LD8T = [&](const u16* s, int row, int k8) {
    return __builtin_bit_cast(
        bf16x8, reinterpret_cast<const uint4*>(s)[row * 8 + (k8 ^ (row & 7))]);
  };

  f32x4 acc[4];
#pragma unroll
  for (int ct = 0; ct < 4; ++ct) acc[ct] = {0.f, 0.f, 0.f, 0.f};

  for (int c = 0; c < 8; ++c) {
    const int k0 = c * 64;
    __syncthreads();
#pragma unroll
    for (int m = 0; m < 2; ++m) {
      int f = m * 512 + tid;
      int srow = f >> 3, sk8 = f & 7;
      int slot = srow * 8 + (sk8 ^ (srow & 7));
      reinterpret_cast<uint4*>(XHs)[slot] = *reinterpret_cast<const uint4*>(
          Xh + (size_t)(m0 + srow) * 512 + k0 + sk8 * 8);
      reinterpret_cast<uint4*>(XLs)[slot] = *reinterpret_cast<const uint4*>(
          Xl + (size_t)(m0 + srow) * 512 + k0 + sk8 * 8);
    }
    {
      int wrow = tid >> 3, wk8 = tid & 7;
      int slot = wrow * 8 + (wk8 ^ (wrow & 7));
      reinterpret_cast<uint4*>(WHs)[slot] = *reinterpret_cast<const uint4*>(
          WtH + (size_t)(n0 + wrow) * 512 + k0 + wk8 * 8);
      reinterpret_cast<uint4*>(WLs)[slot] = *reinterpret_cast<const uint4*>(
          WtL + (size_t)(n0 + wrow) * 512 + k0 + wk8 * 8);
    }
    __syncthreads();

#pragma unroll
    for (int win = 0; win < 2; ++win) {
      int k8a = win * 4 + kg;
      bf16x8 ah = LD8T(XHs, w * 16 + ln, k8a);
      bf16x8 al = LD8T(XLs, w * 16 + ln, k8a);
#pragma unroll
      for (int ct = 0; ct < 4; ++ct) {
        bf16x8 bh = LD8T(WHs, ct * 16 + ln, k8a);
        bf16x8 bl = LD8T(WLs, ct * 16 + ln, k8a);
        acc[ct] = MFMA(ah, bh, acc[ct]);
        acc[ct] = MFMA(al, bh, acc[ct]);
        acc[ct] = MFMA(ah, bl, acc[ct]);
      }
    }
  }

  const int trow0 = m0 + w * 16 + kg * 4;
  if (cy < 12) {
#pragma unroll
    for (int j = 0; j < 4; ++j) {
      int row = trow0 + j, b = row >> 10, t = row & 1023;
      float* OP;
      size_t base;
      if (cy < 8) {
        OP = Q;
        base = ((size_t)(b * HH + cy) * TT + t) * 64;
      } else {
        OP = Kt;
        base = ((size_t)(b * KVHN + (cy - 8)) * TT + t) * 64;
      }
#pragma unroll
      for (int ct = 0; ct < 2; ++ct) {
        int dd = ct * 16 + ln;
        float cc = cosb[t * 32 + dd], ss = sinb[t * 32 + dd];
        float v1 = acc[ct][j], v2 = acc[ct + 2][j];
        OP[base + dd] = v1 * cc + v2 * ss;
        OP[base + 32 + dd] = v2 * cc - v1 * ss;
      }
    }
  } else {
#pragma unroll
    for (int j = 0; j < 4; ++j) {
      int row = trow0 + j, b = row >> 10, t = row & 1023;
      size_t base = ((size_t)(b * KVHN + (cy - 12)) * TT + t) * 64;
#pragma unroll
      for (int ct = 0; ct < 4; ++ct) Vt[base + ct * 16 + ln] = acc[ct][j];
    }
  }
}

// ---------------------------------------------------------------------------
// K2: MFMA causal logits + exp -> A (bf16). Grid (16 sys, 136 n). (r20)
// ---------------------------------------------------------------------------
__global__ __launch_bounds__(256) void logits_mfma_kernel(
    const float* __restrict__ Q, const float* __restrict__ Kt,
    u16* __restrict__ A, float* __restrict__ part) {
  const int sys = blockIdx.x, n = blockIdx.y;
  int it = 0;
  while ((it + 1) * (it + 2) / 2 <= n) ++it;
  const int jt = n - it * (it + 1) / 2;
  const int b = sys >> 3, kvh = (sys & 7) >> 1;
  const int tid = threadIdx.x;
  const int lane = tid & 63, w = tid >> 6;
  const int ln = lane & 15, kg = lane >> 4;
  const int m0 = w * 16;

  const float* Qr = Q + ((size_t)sys * TT + it * 64 + m0 + ln) * 64;
  const float* Kb = Kt + ((size_t)(b * KVHN + kvh) * TT + jt * 64) * 64;
  u16* Aout = A + ((size_t)sys << 20);

  bf16x8 qh0, ql0, qh1, ql1;
  cvt8(Qr + kg * 8, qh0, ql0);
  cvt8(Qr + 32 + kg * 8, qh1, ql1);

  f32x4 acc[4];
#pragma unroll
  for (int ct = 0; ct < 4; ++ct) {
    const float* Kr = Kb + (size_t)(ct * 16 + ln) * 64;
    bf16x8 kh0, kl0, kh1, kl1;
    cvt8(Kr + kg * 8, kh0, kl0);
    cvt8(Kr + 32 + kg * 8, kh1, kl1);
    f32x4 a = {0.f, 0.f, 0.f, 0.f};
    a = MFMA(qh0, kh0, a);
    a = MFMA(qh1, kh1, a);
    a = MFMA(qh0, kl0, a);
    a = MFMA(qh1, kl1, a);
    a = MFMA(ql0, kh0, a);
    a = MFMA(ql1, kh1, a);
    acc[ct] = a;
  }

  const int grow0 = it * 64 + m0;
  const bool full = (jt < it);
  float s[4] = {0.f, 0.f, 0.f, 0.f};
#pragma unroll
  for (int ct = 0; ct < 4; ++ct) {
    int col = jt * 64 + ct * 16 + ln;
#pragma unroll
    for (int j = 0; j < 4; ++j) {
      int row = grow0 + kg * 4 + j;
      float e = (full || col <= row) ? __expf(acc[ct][j] * 0.125f) : 0.f;
      s[j] += e;
      Aout[(size_t)row * 1024 + col] = bfr(e);
    }
  }

#pragma unroll
  for (int off = 1; off < 16; off <<= 1) {
#pragma unroll
    for (int j = 0; j < 4; ++j) s[j] += __shfl_xor(s[j], off);
  }
  if (ln == 0) {
#pragma unroll
    for (int j = 0; j < 4; ++j)
      part[((size_t)(sys * 16 + jt)) * 1024 + grow0 + kg * 4 + j] = s[j];
  }
}

// ---------------------------------------------------------------------------
// K3a: barrier-free one-wave diag-block inversion. (round-15 proven)
// ---------------------------------------------------------------------------
__global__ __launch_bounds__(64) void diaginv_kernel(
    u16* __restrict__ A, const float* __restrict__ part,
    float* __restrict__ invs) {
  const int k = blockIdx.x, sys = blockIdx.y;
  const int c = threadIdx.x;

  u16* Ab = A + ((size_t)sys << 20) + (size_t)(k * 64) * 1024 + k * 64;

  __shared__ float MsT[64][68];
  __shared__ float dv[64];

  {
    const int r = c;
    float row[64];
#pragma unroll
    for (int m8 = 0; m8 < 8; ++m8) {
      uint4 v = *reinterpret_cast<const uint4*>(Ab + (size_t)r * 1024 + m8 * 8);
      row[m8 * 8 + 0] = bflo(v.x); row[m8 * 8 + 1] = bfhi(v.x);
      row[m8 * 8 + 2] = bflo(v.y); row[m8 * 8 + 3] = bfhi(v.y);
      row[m8 * 8 + 4] = bflo(v.z); row[m8 * 8 + 5] = bfhi(v.z);
      row[m8 * 8 + 6] = bflo(v.w); row[m8 * 8 + 7] = bfhi(v.w);
    }
    float s = 0.f;
    for (int jt = 0; jt <= k; ++jt)
      s += part[((size_t)(sys * 16 + jt)) * 1024 + k * 64 + r];
    float svr = 1.0f / s;
    invs[sys * 1024 + k * 64 + r] = svr;
    dv[r] = 1.0f / (1.0f + svr * row[r]);
#pragma unroll
    for (int j = 0; j < 64; ++j) MsT[j][r] = svr * row[j];
  }
  __syncthreads();

  float dvr[64];
#pragma unroll
  for (int q = 0; q < 64; ++q) dvr[q] = dv[q];

  float w[64], acc[64];
#pragma unroll
  for (int r = 0; r < 64; ++r) acc[r] = 0.f;

#pragma unroll
  for (int r = 0; r < 64; ++r) {
    float wr = ((r == c) ? 1.0f : 0.0f) - acc[r];
    wr *= dvr[r];
    w[r] = wr;
#pragma unroll
    for (int q = (r + 1) >> 2; q < 16; ++q) {
      float4 m4 = *reinterpret_cast<const float4*>(&MsT[r][q * 4]);
      acc[q * 4 + 0] += m4.x * wr;
      acc[q * 4 + 1] += m4.y * wr;
      acc[q * 4 + 2] += m4.z * wr;
      acc[q * 4 + 3] += m4.w * wr;
    }
  }

#pragma unroll
  for (int r = 0; r < 64; ++r) Ab[(size_t)r * 1024 + c] = bfr(w[r]);
}

// ---------------------------------------------------------------------------
// K3b: right-looking MFMA solve — EXACT round-16/22 version (proven 47.5 us).
// FROZEN.
// ---------------------------------------------------------------------------
__global__ __launch_bounds__(1024) void solve_mfma_kernel(
    const u16* __restrict__ A, const float* __restrict__ invs,
    const float* __restrict__ Vt, float* __restrict__ Yout) {
  const int sys = blockIdx.x, cq = blockIdx.y;
  const int bb = sys >> 3, kvh = (sys & 7) >> 1;
  const int c0 = cq * 16;
  const int tid = threadIdx.x;
  const int lane = tid & 63, w = tid >> 6;
  const int ln = lane & 15, kg = lane >> 4;

  const u16* Ab = A + ((size_t)sys << 20);
  const float* Vb = Vt + ((size_t)(bb * KVHN + kvh) * TT) * 64;
  float* Yg = Yout + (size_t)sys * TT * 64;

  __shared__ float U[16][1031];
  __shared__ u16 yh[16 * 64], yl[16 * 64];
  __shared__ u16 uh[16 * 64], ul[16 * 64];

  {
    float* Uf = &U[0][0];
    for (int i = tid; i < 16 * 1031; i += 1024) Uf[i] = 0.f;
  }
  __syncthreads();

  for (int k = 0; k < 16; ++k) {
    const int rg0 = k * 64;

    uint4 pm0 = {}, pm1 = {};
    f32x4 pv = {0.f, 0.f, 0.f, 0.f}, psi = {0.f, 0.f, 0.f, 0.f};
    if (w < 4) {
      const u16* mrow = Ab + (size_t)(rg0 + w * 16 + ln) * 1024 + rg0;
      pm0 = *reinterpret_cast<const uint4*>(mrow + kg * 8);
      pm1 = *reinterpret_cast<const uint4*>(mrow + 32 + kg * 8);
#pragma unroll
      for (int j = 0; j < 4; ++j) {
        int gr = rg0 + w * 16 + kg * 4 + j;
        pv[j] = Vb[(size_t)gr * 64 + c0 + ln];
        psi[j] = invs[sys * 1024 + gr];
      }
    }
    const int nu = (15 - k) * 4;
    uint4 pa0[4], pa1[4];
    bool val[4];
#pragma unroll
    for (int t = 0; t < 4; ++t) {
      int un = w + 16 * t;
      val[t] = un < nu;
      if (val[t]) {
        const u16* ar =
            Ab + (size_t)((k + 1 + (un >> 2)) * 64 + (un & 3) * 16 + ln) * 1024 +
            rg0;
        pa0[t] = *reinterpret_cast<const uint4*>(ar + kg * 8);
        pa1[t] = *reinterpret_cast<const uint4*>(ar + 32 + kg * 8);
      }
    }
    __builtin_amdgcn_sched_barrier(0);  // pin: loads issue BEFORE phases

    if (w < 4) {
      f32x4 u;
#pragma unroll
      for (int j = 0; j < 4; ++j) {
        int gr = rg0 + w * 16 + kg * 4 + j;
        u[j] = pv[j] - psi[j] * U[ln][gr];
      }
      st_split_lds(uh, ul, ln, w * 16 + kg * 4, u);
    }
    __syncthreads();

    if (w < 4) {
      bf16x8 ma0 = __builtin_bit_cast(bf16x8, pm0);
      bf16x8 ma1 = __builtin_bit_cast(bf16x8, pm1);
      f32x4 y = {0.f, 0.f, 0.f, 0.f};
      y = MFMA(ma0, ld8_lds(uh, ln, kg), y);
      y = MFMA(ma1, ld8_lds(uh, ln, 4 + kg), y);
      y = MFMA(ma0, ld8_lds(ul, ln, kg), y);
      y = MFMA(ma1, ld8_lds(ul, ln, 4 + kg), y);
#pragma unroll
      for (int j = 0; j < 4; ++j)
        Yg[(size_t)(rg0 + w * 16 + kg * 4 + j) * 64 + c0 + ln] = y[j];
      st_split_lds(yh, yl, ln, w * 16 + kg * 4, y);
    }
    __syncthreads();

#pragma unroll
    for (int t = 0; t < 4; ++t) {
      if (val[t]) {
        int un = w + 16 * t;
        int rb = (k + 1 + (un >> 2)) * 64 + (un & 3) * 16 + kg * 4;
        bf16x8 a0 = __builtin_bit_cast(bf16x8, pa0[t]);
        bf16x8 a1 = __builtin_bit_cast(bf16x8, pa1[t]);
        f32x4 s = {0.f, 0.f, 0.f, 0.f};
        s = MFMA(a0, ld8_lds(yh, ln, kg), s);
        s = MFMA(a1, ld8_lds(yh, ln, 4 + kg), s);
        s = MFMA(a0, ld8_lds(yl, ln, kg), s);
        s = MFMA(a1, ld8_lds(yl, ln, 4 + kg), s);
#pragma unroll
        for (int j = 0; j < 4; ++j) U[ln][rb + j] += s[j];
      }
    }
    __syncthreads();
  }
}

// ---------------------------------------------------------------------------
// K4: out = x + Y2d @ Wo via MFMA, 128x64 LDS-staged tile. (round-22 proven)
// ---------------------------------------------------------------------------
__global__ __launch_bounds__(512) void out_proj_mfma_kernel(
    const float* __restrict__ Y, const u16* __restrict__ WotH,
    const u16* __restrict__ WotL, const float* __restrict__ x,
    float* __restrict__ out) {
  const int cy = blockIdx.x, rt = blockIdx.y;
  const int tid = threadIdx.x;
  const int lane = tid & 63, w = tid >> 6;
  const int ln = lane & 15, kg = lane >> 4;
  const int n0 = cy * 64, m0 = rt * 128;

  __shared__ u16 YHs[128 * 64], YLs[128 * 64];
  __shared__ u16 WHs[64 * 64], WLs[64 * 64];

  auto LD8T = [&](const u16* s, int row, int k8) {
    return __builtin_bit_cast(
        bf16x8, reinterpret_cast<const uint4*>(s)[row * 8 + (k8 ^ (row & 7))]);
  };

  f32x4 acc[4];
#pragma unroll
  for (int ct = 0; ct < 4; ++ct) acc[ct] = {0.f, 0.f, 0.f, 0.f};

  for (int c = 0; c < 8; ++c) {
    const int k0 = c * 64;
    __syncthreads();
#pragma unroll
    for (int m = 0; m < 2; ++m) {
      int f = m * 512 + tid;
      int srow = f >> 3, sk8 = f & 7;
      int slot = srow * 8 + (sk8 ^ (srow & 7));
      int row = m0 + srow, b = row >> 10, t = row & 1023;
      const float* yp = Y + ((size_t)(b * HH + c) * TT + t) * 64 + sk8 * 8;
      bf16x8 h, l;
      cvt8(yp, h, l);
      reinterpret_cast<uint4*>(YHs)[slot] = __builtin_bit_cast(uint4, h);
      reinterpret_cast<uint4*>(YLs)[slot] = __builtin_bit_cast(uint4, l);
    }
    {
      int wrow = tid >> 3, wk8 = tid & 7;
      int slot = wrow * 8 + (wk8 ^ (wrow & 7));
      reinterpret_cast<uint4*>(WHs)[slot] = *reinterpret_cast<const uint4*>(
          WotH + (size_t)(n0 + wrow) * 512 + k0 + wk8 * 8);
      reinterpret_cast<uint4*>(WLs)[slot] = *reinterpret_cast<const uint4*>(
          WotL + (size_t)(n0 + wrow) * 512 + k0 + wk8 * 8);
    }
    __syncthreads();

#pragma unroll
    for (int win = 0; win < 2; ++win) {
      int k8a = win * 4 + kg;
      bf16x8 ah = LD8T(YHs, w * 16 + ln, k8a);
      bf16x8 al = LD8T(YLs, w * 16 + ln, k8a);
#pragma unroll
      for (int ct = 0; ct < 4; ++ct) {
        bf16x8 bh = LD8T(WHs, ct * 16 + ln, k8a);
        bf16x8 bl = LD8T(WLs, ct * 16 + ln, k8a);
        acc[ct] = MFMA(ah, bh, acc[ct]);
        acc[ct] = MFMA(al, bh, acc[ct]);
        acc[ct] = MFMA(ah, bl, acc[ct]);
      }
    }
  }

  const int trow0 = m0 + w * 16 + kg * 4;
#pragma unroll
  for (int j = 0; j < 4; ++j) {
    size_t row = (size_t)(trow0 + j);
#pragma unroll
    for (int ct = 0; ct < 4; ++ct) {
      int col = n0 + ct * 16 + ln;
      out[row * 512 + col] = x[row * 512 + col] + acc[ct][j];
    }
  }
}

// ---------------------------------------------------------------------------
extern "C" void kernel_launch(void* const* d_in, const int* in_sizes, int n_in,
                              void* d_out, int out_size, void* d_ws,
                              size_t ws_size, hipStream_t stream) {
  (void)in_sizes; (void)n_in; (void)out_size; (void)ws_size;
  const float* x = (const float*)d_in[0];
  const float* cosb = (const float*)d_in[1];
  const float* sinb = (const float*)d_in[2];
  const float* Wq = (const float*)d_in[3];
  const float* Wk = (const float*)d_in[4];
  const float* Wv = (const float*)d_in[5];
  const float* Wo = (const float*)d_in[6];
  float* out = (float*)d_out;

  float* ws = (float*)d_ws;
  float* Q = ws;                        // 1,048,576 f
  float* Kt = Q + (size_t)1048576;      //   524,288 f
  float* Vt = Kt + (size_t)524288;      //   524,288 f
  float* Yb = Vt + (size_t)524288;      // 1,048,576 f
  float* invs = Yb + (size_t)1048576;   //    16,384 f
  float* part = invs + (size_t)16384;   //   262,144 f
  u16* A = (u16*)(part + 262144);       // 16,777,216 u16 = 32 MB
  u16* WtH = A + (size_t)16777216;      //   524,288 u16
  u16* WtL = WtH + (size_t)524288;
  u16* WotH = WtL + (size_t)524288;     //   262,144 u16
  u16* WotL = WotH + (size_t)262144;
  u16* Xh = WotL + (size_t)262144;      // 1,048,576 u16
  u16* Xl = Xh + (size_t)1048576;       // total ~55 MB

  prep_kernel<<<dim3(8, 56), 256, 0, stream>>>(x, Wq, Wk, Wv, Wo, WtH, WtL,
                                               WotH, WotL, Xh, Xl);
  qkv_mfma_kernel<<<dim3(16, 16), 512, 0, stream>>>(Xh, Xl, WtH, WtL, cosb,
                                                    sinb, Q, Kt, Vt);
  logits_mfma_kernel<<<dim3(16, 136), 256, 0, stream>>>(Q, Kt, A, part);
  diaginv_kernel<<<dim3(16, 16), 64, 0, stream>>>(A, part, invs);
  solve_mfma_kernel<<<dim3(16, 4), 1024, 0, stream>>>(A, invs, Vt, Yb);
  out_proj_mfma_kernel<<<dim3(8, 16), 512, 0, stream>>>(Yb, WotH, WotL, x, out);
}